// Round 4
// baseline (39.640 us; speedup 1.0000x reference)
//
#include <hip/hip_runtime.h>
#include <math.h>

#define NPTS 4096
#define BLK 256
#define NUNITS 16                     // 8 batches * 2 directions
#define QG 256                        // queries per block
#define QGRPS 16                      // q-groups per unit
#define GRID1 (NUNITS * QGRPS)        // 256 blocks
#define HALF_T 2048                   // targets staged per LDS phase
#define CNT 12288.0f                  // N*D elements per std

typedef _Float16 half8 __attribute__((ext_vector_type(8)));
typedef float f32x16 __attribute__((ext_vector_type(16)));

__device__ __forceinline__ unsigned umin2(unsigned a, unsigned b) { return a < b ? a : b; }
__device__ __forceinline__ unsigned umin3(unsigned a, unsigned b, unsigned c) {
  return umin2(umin2(a, b), c);      // LLVM fuses to v_min3_u32
}

// Per-tile argmin fold: pack (d2 top-20 bits | target index low 12) and
// min3-reduce the 16 regs into the running accumulator. Row bits for reg r:
// (r&3)+8*(r>>2) (bits {0,1,3,4}); the per-lane 4*(lane>>5) bit 2 is OR-ed
// once after the whole loop (lane-constant, order-safe).
__device__ __forceinline__ unsigned tilemin(const f32x16 d, unsigned ob, unsigned kacc) {
  unsigned k[16];
  #pragma unroll
  for (int r = 0; r < 16; ++r) {
    const unsigned row = (unsigned)((r & 3) + 8 * (r >> 2));
    k[r] = (__float_as_uint(d[r]) & 0xFFFFF000u) | (ob + row);   // v_and_or_b32
  }
  const unsigned a0 = umin3(k[0],  k[1],  k[2]);
  const unsigned a1 = umin3(k[3],  k[4],  k[5]);
  const unsigned a2 = umin3(k[6],  k[7],  k[8]);
  const unsigned a3 = umin3(k[9],  k[10], k[11]);
  const unsigned a4 = umin3(k[12], k[13], k[14]);
  const unsigned b0 = umin3(a0, a1, a2);
  const unsigned b1 = umin3(a3, a4, k[15]);
  return umin3(b0, b1, kacc);
}

// ---------------------------------------------------------------------------
// Kernel 1: fused full-scan NN. Each block owns 256 queries of one unit and
// scans ALL 4096 targets (two 2048-target LDS phases), so the argmin key is
// final in-register: gather exact fp32 residual and emit one float2 partial.
// fp16-split d2 via ONE 32x32x16 f16 MFMA per tile (proven round 3):
//  k0-2: bh*(-2ah)  k3-5: bl*(-2ah)  k6-8: bh*(-2al)
//  k9,10: b2{h,l}*1  k11,12: 1*a2{h,l}  k13-15: 0
// ---------------------------------------------------------------------------
__global__ __launch_bounds__(BLK) void nn_fused_kernel(
    const float* __restrict__ x, const float* __restrict__ y,
    float2* __restrict__ partials) {
  __shared__ half8 Ap[2 * HALF_T];   // 64 KB: plane [hi5][2048] (conflict-free reads)
  __shared__ half8 Bq[2 * QG];       //  8 KB: plane [hi5][256]
  __shared__ float wS[4], wSS[4];

  const int bid = blockIdx.x;
  const int unit = bid >> 4, qgrp = bid & 15;
  const int b = unit >> 1, dir = unit & 1;
  const float* __restrict__ Q = (dir ? y : x) + (size_t)b * NPTS * 3;  // queries
  const float* __restrict__ T = (dir ? x : y) + (size_t)b * NPTS * 3;  // targets

  const int tid = threadIdx.x;
  const _Float16 one  = (_Float16)1.0f;
  const _Float16 zero = (_Float16)0.0f;
  const _Float16 n2   = (_Float16)(-2.0f);

  // ---- pack this block's 256 queries (one per thread) ----
  {
    const int qg = qgrp * QG + tid;
    const float ax = Q[3 * qg], ay = Q[3 * qg + 1], az = Q[3 * qg + 2];
    const float a2 = fmaf(ax, ax, fmaf(ay, ay, az * az));
    const _Float16 ah0 = (_Float16)ax, ah1 = (_Float16)ay, ah2 = (_Float16)az;
    const _Float16 al0 = (_Float16)(ax - (float)ah0);
    const _Float16 al1 = (_Float16)(ay - (float)ah1);
    const _Float16 al2 = (_Float16)(az - (float)ah2);
    const _Float16 a2h = (_Float16)a2;
    const _Float16 a2l = (_Float16)(a2 - (float)a2h);
    half8 lo, hi;
    lo[0] = n2 * ah0; lo[1] = n2 * ah1; lo[2] = n2 * ah2; lo[3] = n2 * ah0;
    lo[4] = n2 * ah1; lo[5] = n2 * ah2; lo[6] = n2 * al0; lo[7] = n2 * al1;
    hi[0] = n2 * al2; hi[1] = one; hi[2] = one; hi[3] = a2h;
    hi[4] = a2l; hi[5] = zero; hi[6] = zero; hi[7] = zero;
    Bq[tid]      = lo;
    Bq[QG + tid] = hi;
  }

  const int lane = tid & 63, w = tid >> 6, ln = lane & 31, hi5 = lane >> 5;
  unsigned kacc0 = 0xFFFFFFFFu, kacc1 = 0xFFFFFFFFu;
  f32x16 Z;
  #pragma unroll
  for (int r = 0; r < 16; ++r) Z[r] = 0.0f;

  half8 bf0, bf1;
  for (int c = 0; c < 2; ++c) {
    __syncthreads();   // c=0: covers Bq writes; c=1: all waves done reading Ap
    // ---- stage 2048 targets into LDS (8 per thread) ----
    for (int k = 0; k < 8; ++k) {
      const int i  = tid + k * BLK;          // 0..2047
      const int tg = c * HALF_T + i;
      const float bx = T[3 * tg], by = T[3 * tg + 1], bz = T[3 * tg + 2];
      const float b2 = fmaf(bx, bx, fmaf(by, by, bz * bz));
      const _Float16 bh0 = (_Float16)bx, bh1 = (_Float16)by, bh2 = (_Float16)bz;
      const _Float16 bl0 = (_Float16)(bx - (float)bh0);
      const _Float16 bl1 = (_Float16)(by - (float)bh1);
      const _Float16 bl2 = (_Float16)(bz - (float)bh2);
      const _Float16 s2h = (_Float16)b2;
      const _Float16 s2l = (_Float16)(b2 - (float)s2h);
      half8 lo, hi;
      lo[0] = bh0; lo[1] = bh1; lo[2] = bh2; lo[3] = bl0;
      lo[4] = bl1; lo[5] = bl2; lo[6] = bh0; lo[7] = bh1;
      hi[0] = bh2; hi[1] = s2h; hi[2] = s2l; hi[3] = one;
      hi[4] = one; hi[5] = zero; hi[6] = zero; hi[7] = zero;
      Ap[i]          = lo;
      Ap[HALF_T + i] = hi;
    }
    __syncthreads();
    if (c == 0) {
      bf0 = Bq[(hi5 << 8) + w * 64 + ln];        // B[k=8*hi5+e][q]
      bf1 = Bq[(hi5 << 8) + w * 64 + 32 + ln];
    }
    const unsigned cb = (unsigned)(c * HALF_T);
    #pragma unroll 2
    for (int t = 0; t < HALF_T / 32; ++t) {      // 64 tiles per phase
      const half8 af = Ap[(hi5 << 11) + t * 32 + ln];   // A[t0+ln][k=8*hi5+e]
      const f32x16 d0 = __builtin_amdgcn_mfma_f32_32x32x16_f16(af, bf0, Z, 0, 0, 0);
      const f32x16 d1 = __builtin_amdgcn_mfma_f32_32x32x16_f16(af, bf1, Z, 0, 0, 0);
      const unsigned ob = cb + (unsigned)(t * 32);
      kacc0 = tilemin(d0, ob, kacc0);
      kacc1 = tilemin(d1, ob, kacc1);
    }
  }

  // fold deferred per-lane row bit, combine hi/lo 32-row halves
  const unsigned vhib = (unsigned)(hi5 << 2);
  kacc0 |= vhib; kacc1 |= vhib;
  kacc0 = umin2(kacc0, (unsigned)__shfl_xor((int)kacc0, 32));
  kacc1 = umin2(kacc1, (unsigned)__shfl_xor((int)kacc1, 32));

  // exact fp32 residuals for this lane's 2 queries (lanes 0..31)
  float s = 0.f, ss = 0.f;
  if (lane < 32) {
    const int q0 = qgrp * QG + w * 64 + ln;
    const int q1 = q0 + 32;
    const int j0 = (int)(kacc0 & 4095u);
    const int j1 = (int)(kacc1 & 4095u);
    const float r0x = Q[3 * q0]     - T[3 * j0];
    const float r0y = Q[3 * q0 + 1] - T[3 * j0 + 1];
    const float r0z = Q[3 * q0 + 2] - T[3 * j0 + 2];
    const float r1x = Q[3 * q1]     - T[3 * j1];
    const float r1y = Q[3 * q1 + 1] - T[3 * j1 + 1];
    const float r1z = Q[3 * q1 + 2] - T[3 * j1 + 2];
    s  = (r0x + r0y + r0z) + (r1x + r1y + r1z);
    ss = fmaf(r0x, r0x, fmaf(r0y, r0y, r0z * r0z)) +
         fmaf(r1x, r1x, fmaf(r1y, r1y, r1z * r1z));
  }
  #pragma unroll
  for (int off = 32; off > 0; off >>= 1) {
    s  += __shfl_down(s, off);
    ss += __shfl_down(ss, off);
  }
  if ((tid & 63) == 0) { wS[w] = s; wSS[w] = ss; }
  __syncthreads();
  if (tid == 0) {
    partials[bid] = make_float2(wS[0] + wS[1] + wS[2] + wS[3],
                                wSS[0] + wSS[1] + wSS[2] + wSS[3]);
  }
}

// ---------------------------------------------------------------------------
// Kernel 2: deterministic finalize. partials[bid] with bid = unit*16 + qgrp.
// ---------------------------------------------------------------------------
__global__ __launch_bounds__(256) void finalize_kernel(
    const float2* __restrict__ partials, float* __restrict__ out) {
  __shared__ float2 sh[GRID1];
  __shared__ float sig[NUNITS];

  sh[threadIdx.x] = partials[threadIdx.x];
  __syncthreads();

  if (threadIdx.x < NUNITS) {
    float S = 0.f, SS = 0.f;
    #pragma unroll
    for (int i = 0; i < QGRPS; ++i) {
      S  += sh[threadIdx.x * QGRPS + i].x;
      SS += sh[threadIdx.x * QGRPS + i].y;
    }
    const float var = (SS - S * S / CNT) / (CNT - 1.0f);
    sig[threadIdx.x] = sqrtf(fmaxf(var, 0.0f));
  }
  __syncthreads();

  if (threadIdx.x == 0) {
    float acc = 0.f;
    #pragma unroll
    for (int b = 0; b < 8; ++b) acc += fmaxf(sig[2 * b], sig[2 * b + 1]);
    out[0] = acc * 0.125f;
  }
}

// ---------------------------------------------------------------------------
extern "C" void kernel_launch(void* const* d_in, const int* in_sizes, int n_in,
                              void* d_out, int out_size, void* d_ws, size_t ws_size,
                              hipStream_t stream) {
  const float* x = (const float*)d_in[0];
  const float* y = (const float*)d_in[1];
  float* out = (float*)d_out;
  float2* partials = (float2*)d_ws;   // 256 * 8 B = 2 KB scratch

  hipLaunchKernelGGL(nn_fused_kernel, dim3(GRID1), dim3(BLK), 0, stream,
                     x, y, partials);
  hipLaunchKernelGGL(finalize_kernel, dim3(1), dim3(256), 0, stream,
                     partials, out);
}

// Round 5
// 25.624 us; speedup vs baseline: 1.5470x; 1.5470x over previous
//
#include <hip/hip_runtime.h>
#include <math.h>

#define NPTS 4096
#define BLK 256
#define NUNITS 16                    // 8 batches * 2 directions
#define CHUNKS 16                    // target chunks per unit
#define CSZ 256                      // targets per chunk
#define TILES 8                      // 32-target tiles per chunk
#define QGRP 256                     // queries per block (kernel 1)
#define QGRPS 16                     // query groups per unit
#define GRID1 (NUNITS * QGRPS * CHUNKS)  // 4096 blocks
#define GRID2 (NUNITS * QGRPS)           // 256 blocks
#define CNT 12288.0f                 // N*D elements per std
#define KEY_BYTES ((size_t)NUNITS * CHUNKS * NPTS * 4)   // 4 MB

typedef _Float16 half8 __attribute__((ext_vector_type(8)));
typedef float f32x16 __attribute__((ext_vector_type(16)));

__device__ __forceinline__ unsigned umin2(unsigned a, unsigned b) { return a < b ? a : b; }
__device__ __forceinline__ float fmin3(float a, float b, float c) {
  return fminf(fminf(a, b), c);      // fuses to v_min3_f32
}

// min over the 16 f32 accumulator regs of one 32x32 MFMA result (8 min3-ish ops)
__device__ __forceinline__ float tilemin16(const f32x16 d) {
  const float a0 = fmin3(d[0],  d[1],  d[2]);
  const float a1 = fmin3(d[3],  d[4],  d[5]);
  const float a2 = fmin3(d[6],  d[7],  d[8]);
  const float a3 = fmin3(d[9],  d[10], d[11]);
  const float a4 = fmin3(d[12], d[13], d[14]);
  return fminf(fmin3(a0, a1, a2), fmin3(a3, a4, d[15]));
}

// ---------------------------------------------------------------------------
// Kernel 1: per (unit, query, chunk) hierarchical argmin key.
// fp16-split d2 via ONE 32x32x16 f16 MFMA per 32-target tile (proven r3/r4):
//  k0-2: bh*(-2ah)  k3-5: bl*(-2ah)  k6-8: bh*(-2al)
//  k9,10: b2{h,l}*1  k11,12: 1*a2{h,l}  k13-15: 0
// Hot loop tracks only (trunc tile-min | tile-id): 8 fmin + 1 and_or + 1 umin
// per tile-col. Winning 32-row tile is resolved exactly in kernel 2.
// ---------------------------------------------------------------------------
__global__ __launch_bounds__(BLK, 4) void keys_kernel(
    const float* __restrict__ x, const float* __restrict__ y,
    unsigned* __restrict__ keys) {
  __shared__ half8 Ap[2 * CSZ];    // 8 KB: plane [hi5][256 targets]
  __shared__ half8 Bq[2 * QGRP];   // 8 KB: plane [hi5][256 queries]

  const int bid   = blockIdx.x;
  const int unit  = bid >> 8;          // 256 blocks per unit
  const int qg    = (bid >> 4) & 15;
  const int chunk = bid & 15;
  const int b = unit >> 1, dir = unit & 1;
  const float* __restrict__ Q = (dir ? y : x) + (size_t)b * NPTS * 3;  // queries
  const float* __restrict__ T = (dir ? x : y) + (size_t)b * NPTS * 3;  // targets

  const int tid = threadIdx.x;
  const _Float16 one  = (_Float16)1.0f;
  const _Float16 zero = (_Float16)0.0f;
  const _Float16 n2   = (_Float16)(-2.0f);

  // ---- pack one target row per thread ----
  {
    const int tg = chunk * CSZ + tid;
    const float bx = T[3 * tg], by = T[3 * tg + 1], bz = T[3 * tg + 2];
    const float b2 = fmaf(bx, bx, fmaf(by, by, bz * bz));
    const _Float16 bh0 = (_Float16)bx, bh1 = (_Float16)by, bh2 = (_Float16)bz;
    const _Float16 bl0 = (_Float16)(bx - (float)bh0);
    const _Float16 bl1 = (_Float16)(by - (float)bh1);
    const _Float16 bl2 = (_Float16)(bz - (float)bh2);
    const _Float16 s2h = (_Float16)b2;
    const _Float16 s2l = (_Float16)(b2 - (float)s2h);
    half8 lo, hi;
    lo[0] = bh0; lo[1] = bh1; lo[2] = bh2; lo[3] = bl0;
    lo[4] = bl1; lo[5] = bl2; lo[6] = bh0; lo[7] = bh1;
    hi[0] = bh2; hi[1] = s2h; hi[2] = s2l; hi[3] = one;
    hi[4] = one; hi[5] = zero; hi[6] = zero; hi[7] = zero;
    Ap[tid]       = lo;
    Ap[CSZ + tid] = hi;
  }
  // ---- pack one query column per thread ----
  {
    const int qq = qg * QGRP + tid;
    const float ax = Q[3 * qq], ay = Q[3 * qq + 1], az = Q[3 * qq + 2];
    const float a2 = fmaf(ax, ax, fmaf(ay, ay, az * az));
    const _Float16 ah0 = (_Float16)ax, ah1 = (_Float16)ay, ah2 = (_Float16)az;
    const _Float16 al0 = (_Float16)(ax - (float)ah0);
    const _Float16 al1 = (_Float16)(ay - (float)ah1);
    const _Float16 al2 = (_Float16)(az - (float)ah2);
    const _Float16 a2h = (_Float16)a2;
    const _Float16 a2l = (_Float16)(a2 - (float)a2h);
    half8 lo, hi;
    lo[0] = n2 * ah0; lo[1] = n2 * ah1; lo[2] = n2 * ah2; lo[3] = n2 * ah0;
    lo[4] = n2 * ah1; lo[5] = n2 * ah2; lo[6] = n2 * al0; lo[7] = n2 * al1;
    hi[0] = n2 * al2; hi[1] = one; hi[2] = one; hi[3] = a2h;
    hi[4] = a2l; hi[5] = zero; hi[6] = zero; hi[7] = zero;
    Bq[tid]        = lo;
    Bq[QGRP + tid] = hi;
  }
  __syncthreads();

  const int lane = tid & 63, w = tid >> 6, ln = lane & 31, hi5 = lane >> 5;
  // wave w owns queries w*64 .. w*64+63 (2 column tiles)
  const half8 bf0 = Bq[hi5 * QGRP + w * 64 + ln];
  const half8 bf1 = Bq[hi5 * QGRP + w * 64 + 32 + ln];

  f32x16 Z;
  #pragma unroll
  for (int r = 0; r < 16; ++r) Z[r] = 0.0f;

  unsigned kacc0 = 0xFFFFFFFFu, kacc1 = 0xFFFFFFFFu;
  const unsigned pbase = (unsigned)(chunk * TILES);

  #pragma unroll
  for (int t = 0; t < TILES; ++t) {
    const half8 af = Ap[hi5 * CSZ + t * 32 + ln];
    const f32x16 d0 = __builtin_amdgcn_mfma_f32_32x32x16_f16(af, bf0, Z, 0, 0, 0);
    const f32x16 d1 = __builtin_amdgcn_mfma_f32_32x32x16_f16(af, bf1, Z, 0, 0, 0);
    const unsigned pay = pbase + (unsigned)t;
    const float m0 = tilemin16(d0);
    const float m1 = tilemin16(d1);
    kacc0 = umin2(kacc0, (__float_as_uint(m0) & 0xFFFFF000u) | pay);
    kacc1 = umin2(kacc1, (__float_as_uint(m1) & 0xFFFFF000u) | pay);
  }

  // merge the two 16-row halves of each tile (key carries tile-id only)
  kacc0 = umin2(kacc0, (unsigned)__shfl_xor((int)kacc0, 32));
  kacc1 = umin2(kacc1, (unsigned)__shfl_xor((int)kacc1, 32));

  if (lane < 32) {
    const unsigned kb = (unsigned)((unit * CHUNKS + chunk) << 12);
    const unsigned q0 = (unsigned)(qg * QGRP + w * 64 + ln);
    keys[kb | q0]        = kacc0;
    keys[kb | (q0 + 32)] = kacc1;
  }
}

// ---------------------------------------------------------------------------
// Kernel 2: per query, min the 16 chunk keys -> winning 32-target tile;
// re-scan that tile in exact fp32 (first-index tie-break), residual,
// deterministic per-block (sum, sumsq) partial.
// ---------------------------------------------------------------------------
__global__ __launch_bounds__(BLK) void resolve_kernel(
    const float* __restrict__ x, const float* __restrict__ y,
    const unsigned* __restrict__ keys, float2* __restrict__ partials) {
  __shared__ float wS[4], wSS[4];

  const int bid  = blockIdx.x;       // unit*16 + qblk
  const int unit = bid >> 4;
  const int b = unit >> 1, dir = unit & 1;
  const float* __restrict__ Q = (dir ? y : x) + (size_t)b * NPTS * 3;
  const float* __restrict__ T = (dir ? x : y) + (size_t)b * NPTS * 3;
  const int q = ((bid & 15) << 8) + (int)threadIdx.x;

  unsigned bk = 0xFFFFFFFFu;
  #pragma unroll
  for (int c = 0; c < CHUNKS; ++c) {
    bk = umin2(bk, keys[((unsigned)(unit * CHUNKS + c) << 12) | (unsigned)q]);
  }
  const int tbase = (int)(bk & 4095u) * 32;   // payload = chunk*8 + tile, *32 -> row base

  const float qx = Q[3 * q], qy = Q[3 * q + 1], qz = Q[3 * q + 2];
  unsigned best = 0xFFFFFFFFu;
  #pragma unroll 8
  for (int i = 0; i < 32; ++i) {
    const int j = tbase + i;
    const float dx = qx - T[3 * j];
    const float dy = qy - T[3 * j + 1];
    const float dz = qz - T[3 * j + 2];
    const float d2 = fmaf(dx, dx, fmaf(dy, dy, dz * dz));
    // exact fp32 in-tile argmin, first-index tie-break (5 low bits = row)
    best = umin2(best, (__float_as_uint(d2) & 0xFFFFFFE0u) | (unsigned)i);
  }
  const int j = tbase + (int)(best & 31u);

  const float rx = qx - T[3 * j];
  const float ry = qy - T[3 * j + 1];
  const float rz = qz - T[3 * j + 2];
  float s  = rx + ry + rz;
  float ss = fmaf(rx, rx, fmaf(ry, ry, rz * rz));

  #pragma unroll
  for (int off = 32; off > 0; off >>= 1) {
    s  += __shfl_down(s, off);
    ss += __shfl_down(ss, off);
  }
  const int wid = threadIdx.x >> 6;
  if ((threadIdx.x & 63) == 0) { wS[wid] = s; wSS[wid] = ss; }
  __syncthreads();
  if (threadIdx.x == 0) {
    partials[bid] = make_float2(wS[0] + wS[1] + wS[2] + wS[3],
                                wSS[0] + wSS[1] + wSS[2] + wSS[3]);
  }
}

// ---------------------------------------------------------------------------
// Kernel 3: deterministic finalize. partials[bid], bid = unit*16 + qblk.
// ---------------------------------------------------------------------------
__global__ __launch_bounds__(256) void finalize_kernel(
    const float2* __restrict__ partials, float* __restrict__ out) {
  __shared__ float2 sh[GRID2];
  __shared__ float sig[NUNITS];

  sh[threadIdx.x] = partials[threadIdx.x];
  __syncthreads();

  if (threadIdx.x < NUNITS) {
    float S = 0.f, SS = 0.f;
    #pragma unroll
    for (int i = 0; i < QGRPS; ++i) {
      S  += sh[threadIdx.x * QGRPS + i].x;
      SS += sh[threadIdx.x * QGRPS + i].y;
    }
    const float var = (SS - S * S / CNT) / (CNT - 1.0f);
    sig[threadIdx.x] = sqrtf(fmaxf(var, 0.0f));
  }
  __syncthreads();

  if (threadIdx.x == 0) {
    float acc = 0.f;
    #pragma unroll
    for (int b = 0; b < 8; ++b) acc += fmaxf(sig[2 * b], sig[2 * b + 1]);
    out[0] = acc * 0.125f;
  }
}

// ---------------------------------------------------------------------------
extern "C" void kernel_launch(void* const* d_in, const int* in_sizes, int n_in,
                              void* d_out, int out_size, void* d_ws, size_t ws_size,
                              hipStream_t stream) {
  const float* x = (const float*)d_in[0];
  const float* y = (const float*)d_in[1];
  float* out = (float*)d_out;

  unsigned* keys   = (unsigned*)d_ws;                       // 4 MB
  float2*  partials = (float2*)((char*)d_ws + KEY_BYTES);   // + 2 KB

  hipLaunchKernelGGL(keys_kernel, dim3(GRID1), dim3(BLK), 0, stream, x, y, keys);
  hipLaunchKernelGGL(resolve_kernel, dim3(GRID2), dim3(BLK), 0, stream,
                     x, y, keys, partials);
  hipLaunchKernelGGL(finalize_kernel, dim3(1), dim3(256), 0, stream, partials, out);
}